// Round 1
// baseline (6775.394 us; speedup 1.0000x reference)
//
#include <hip/hip_runtime.h>
#include <math.h>

// Problem constants (B,S,D) = (8,4096,1024), fp32 throughout.
#define BB 8
#define SS 4096
#define DD 1024

// ---------------------------------------------------------------------------
// Kernel 1: fused QKV GEMM (NT): C[m,e] = sum_k X[m,k]*W[e,k] + bias[e]
// Both operands are K-contiguous (row-major X, row-major W of shape [e,k]).
// 64x64 output tile, BK=16, 256 threads, 4x4 micro-tile per thread.
// blockIdx.z in {0,1,2} selects (Wk,bk,K) / (Wq,bq,Q) / (Wv,bv,V).
// ---------------------------------------------------------------------------
__global__ __launch_bounds__(256) void qkv_gemm(
    const float* __restrict__ X,
    const float* __restrict__ Wk, const float* __restrict__ bk,
    const float* __restrict__ Wq, const float* __restrict__ bq,
    const float* __restrict__ Wv, const float* __restrict__ bv,
    float* __restrict__ K, float* __restrict__ Q, float* __restrict__ V)
{
    // pitch 17 breaks power-of-2 bank strides; scalar LDS stores keep alignment legal
    __shared__ float As[64][17];
    __shared__ float Bs[64][17];

    const float* W; const float* bias; float* C;
    if (blockIdx.z == 0)      { W = Wk; bias = bk; C = K; }
    else if (blockIdx.z == 1) { W = Wq; bias = bq; C = Q; }
    else                      { W = Wv; bias = bv; C = V; }

    const int t  = threadIdx.x;
    const int m0 = blockIdx.x * 64;
    const int n0 = blockIdx.y * 64;
    const int tx = t & 15, ty = t >> 4;
    const int lr = t >> 2;          // 0..63 (tile row for loads)
    const int lk = (t & 3) * 4;     // 0,4,8,12

    float acc[4][4] = {};

    for (int k0 = 0; k0 < DD; k0 += 16) {
        float4 av = *(const float4*)&X[(size_t)(m0 + lr) * DD + k0 + lk];
        float4 bv4 = *(const float4*)&W[(size_t)(n0 + lr) * DD + k0 + lk];
        As[lr][lk + 0] = av.x; As[lr][lk + 1] = av.y;
        As[lr][lk + 2] = av.z; As[lr][lk + 3] = av.w;
        Bs[lr][lk + 0] = bv4.x; Bs[lr][lk + 1] = bv4.y;
        Bs[lr][lk + 2] = bv4.z; Bs[lr][lk + 3] = bv4.w;
        __syncthreads();
        #pragma unroll
        for (int kk = 0; kk < 16; ++kk) {
            float a[4], b[4];
            #pragma unroll
            for (int i = 0; i < 4; ++i) a[i] = As[ty * 4 + i][kk];
            #pragma unroll
            for (int j = 0; j < 4; ++j) b[j] = Bs[tx * 4 + j][kk];
            #pragma unroll
            for (int i = 0; i < 4; ++i)
                #pragma unroll
                for (int j = 0; j < 4; ++j)
                    acc[i][j] = fmaf(a[i], b[j], acc[i][j]);
        }
        __syncthreads();
    }

    #pragma unroll
    for (int i = 0; i < 4; ++i) {
        const int m = m0 + ty * 4 + i;
        #pragma unroll
        for (int j = 0; j < 4; ++j) {
            const int n = n0 + tx * 4 + j;
            C[(size_t)m * DD + n] = acc[i][j] + bias[n];
        }
    }
}

// ---------------------------------------------------------------------------
// Kernel 2: scores[b,d,e] = (1/32) * sum_s K[b,s,d] * V[b,s,e]   (TN GEMM)
// Tiles: 64x64 over (d,e), BK=16 over s. LDS [s][d] with pitch 68 (float4-safe).
// ---------------------------------------------------------------------------
__global__ __launch_bounds__(256) void ktv_gemm(
    const float* __restrict__ K, const float* __restrict__ V,
    float* __restrict__ Sc)
{
    __shared__ float Ks[16][68];
    __shared__ float Vs[16][68];

    const int bb = blockIdx.z;
    const float* Kb = K + (size_t)bb * SS * DD;
    const float* Vb = V + (size_t)bb * SS * DD;
    float* Sb = Sc + (size_t)bb * DD * DD;

    const int t  = threadIdx.x;
    const int d0 = blockIdx.x * 64;
    const int e0 = blockIdx.y * 64;
    const int tx = t & 15, ty = t >> 4;
    const int si = t >> 4;           // 0..15
    const int dj = (t & 15) * 4;     // 0..60

    float acc[4][4] = {};

    for (int s0 = 0; s0 < SS; s0 += 16) {
        float4 kv = *(const float4*)&Kb[(size_t)(s0 + si) * DD + d0 + dj];
        float4 vv = *(const float4*)&Vb[(size_t)(s0 + si) * DD + e0 + dj];
        *(float4*)&Ks[si][dj] = kv;   // pitch 68 => 16B aligned
        *(float4*)&Vs[si][dj] = vv;
        __syncthreads();
        #pragma unroll
        for (int kk = 0; kk < 16; ++kk) {
            float a[4], b[4];
            #pragma unroll
            for (int i = 0; i < 4; ++i) a[i] = Ks[kk][ty * 4 + i];
            #pragma unroll
            for (int j = 0; j < 4; ++j) b[j] = Vs[kk][tx * 4 + j];
            #pragma unroll
            for (int i = 0; i < 4; ++i)
                #pragma unroll
                for (int j = 0; j < 4; ++j)
                    acc[i][j] = fmaf(a[i], b[j], acc[i][j]);
        }
        __syncthreads();
    }

    const float inv = 0.03125f;  // 1/sqrt(1024)
    #pragma unroll
    for (int i = 0; i < 4; ++i)
        #pragma unroll
        for (int j = 0; j < 4; ++j)
            Sb[(size_t)(d0 + ty * 4 + i) * DD + e0 + tx * 4 + j] = acc[i][j] * inv;
}

// ---------------------------------------------------------------------------
// Kernel 3: softmax over the sequence axis: Q[b,:,d] -> softmax column-wise.
// One thread per (b,d) column; consecutive threads take consecutive d, so
// every row step is a coalesced 1 KB read per wave. Online max/sum then write.
// ---------------------------------------------------------------------------
__global__ __launch_bounds__(256) void softmax_seq(float* __restrict__ Q)
{
    const int d  = blockIdx.x * 256 + threadIdx.x;
    const int bb = blockIdx.y;
    float* base = Q + (size_t)bb * SS * DD + d;

    float m = -INFINITY, l = 0.f;
    for (int s = 0; s < SS; ++s) {
        float x = base[(size_t)s * DD];
        float nm = fmaxf(m, x);
        l = l * __expf(m - nm) + __expf(x - nm);
        m = nm;
    }
    const float invl = 1.f / l;
    for (int s = 0; s < SS; ++s) {
        float x = base[(size_t)s * DD];
        base[(size_t)s * DD] = __expf(x - m) * invl;
    }
}

// ---------------------------------------------------------------------------
// Kernel 4: out[b,s,e] = (1/32) * sum_d Qsm[b,s,d] * scores[b,d,e]  (NN GEMM)
// ---------------------------------------------------------------------------
__global__ __launch_bounds__(256) void attn_out(
    const float* __restrict__ Q, const float* __restrict__ Sc,
    float* __restrict__ O)
{
    __shared__ float As[64][17];
    __shared__ float Bs[16][68];

    const int r0  = blockIdx.x * 64;       // row across the whole batch-group
    const int bb  = r0 / SS;               // batch within group
    const int sr0 = r0 - bb * SS;          // row within batch
    const float* Qb = Q  + (size_t)bb * SS * DD;
    const float* Sb = Sc + (size_t)bb * DD * DD;
    float* Ob = O + (size_t)bb * SS * DD;

    const int t  = threadIdx.x;
    const int e0 = blockIdx.y * 64;
    const int tx = t & 15, ty = t >> 4;
    const int lr = t >> 2;          // A-load row 0..63
    const int lk = (t & 3) * 4;     // A-load col 0,4,8,12
    const int si = t >> 4;          // B-load row 0..15
    const int ej = (t & 15) * 4;    // B-load col

    float acc[4][4] = {};

    for (int k0 = 0; k0 < DD; k0 += 16) {
        float4 av = *(const float4*)&Qb[(size_t)(sr0 + lr) * DD + k0 + lk];
        float4 bv = *(const float4*)&Sb[(size_t)(k0 + si) * DD + e0 + ej];
        As[lr][lk + 0] = av.x; As[lr][lk + 1] = av.y;
        As[lr][lk + 2] = av.z; As[lr][lk + 3] = av.w;
        *(float4*)&Bs[si][ej] = bv;
        __syncthreads();
        #pragma unroll
        for (int kk = 0; kk < 16; ++kk) {
            float a[4], b[4];
            #pragma unroll
            for (int i = 0; i < 4; ++i) a[i] = As[ty * 4 + i][kk];
            #pragma unroll
            for (int j = 0; j < 4; ++j) b[j] = Bs[kk][tx * 4 + j];
            #pragma unroll
            for (int i = 0; i < 4; ++i)
                #pragma unroll
                for (int j = 0; j < 4; ++j)
                    acc[i][j] = fmaf(a[i], b[j], acc[i][j]);
        }
        __syncthreads();
    }

    const float inv = 0.03125f;
    #pragma unroll
    for (int i = 0; i < 4; ++i)
        #pragma unroll
        for (int j = 0; j < 4; ++j)
            Ob[(size_t)(sr0 + ty * 4 + i) * DD + e0 + tx * 4 + j] = acc[i][j] * inv;
}

// ---------------------------------------------------------------------------
extern "C" void kernel_launch(void* const* d_in, const int* in_sizes, int n_in,
                              void* d_out, int out_size, void* d_ws, size_t ws_size,
                              hipStream_t stream)
{
    (void)in_sizes; (void)n_in; (void)out_size;
    const float* X  = (const float*)d_in[0];
    const float* Wk = (const float*)d_in[1];
    const float* bk = (const float*)d_in[2];
    const float* Wq = (const float*)d_in[3];
    const float* bq = (const float*)d_in[4];
    const float* Wv = (const float*)d_in[5];
    const float* bv = (const float*)d_in[6];
    float* out = (float*)d_out;

    // Workspace per batch: k,q,v [S,D] + scores [D,D], fp32.
    const size_t perBatch = ((size_t)3 * SS * DD + (size_t)DD * DD) * sizeof(float);
    int G = (int)(ws_size / perBatch);
    if (G < 1) G = 1;           // if ws is undersized there is no fallback anyway
    if (G > BB) G = BB;

    float* wsf = (float*)d_ws;
    float* Kw = wsf;
    float* Qw = Kw + (size_t)G * SS * DD;
    float* Vw = Qw + (size_t)G * SS * DD;
    float* Sw = Vw + (size_t)G * SS * DD;

    for (int b0 = 0; b0 < BB; b0 += G) {
        const int Gc = (b0 + G <= BB) ? G : (BB - b0);
        const float* Xb = X + (size_t)b0 * SS * DD;
        float* Outb = out + (size_t)b0 * SS * DD;

        // 1) k,q,v = X @ W^T + b
        qkv_gemm<<<dim3(Gc * SS / 64, DD / 64, 3), 256, 0, stream>>>(
            Xb, Wk, bk, Wq, bq, Wv, bv, Kw, Qw, Vw);
        // 2) scores = K^T V / 32
        ktv_gemm<<<dim3(DD / 64, DD / 64, Gc), 256, 0, stream>>>(Kw, Vw, Sw);
        // 3) q = softmax(q, axis=seq)
        softmax_seq<<<dim3(DD / 256, Gc), 256, 0, stream>>>(Qw);
        // 4) out = q @ scores / 32
        attn_out<<<dim3(Gc * SS / 64, DD / 64), 256, 0, stream>>>(Qw, Sw, Outb);
    }
}

// Round 2
// 3616.755 us; speedup vs baseline: 1.8733x; 1.8733x over previous
//
#include <hip/hip_runtime.h>
#include <math.h>

#define BB 8
#define SS 4096
#define DD 1024

typedef __attribute__((ext_vector_type(8))) short short8;   // 8 bf16 (4 VGPRs)
typedef __attribute__((ext_vector_type(4))) float f32x4;    // MFMA C/D

// ---------------- bf16 helpers (manual RNE, no header deps) ----------------
__device__ __forceinline__ unsigned short f2bf(float x) {
    unsigned int u = __float_as_uint(x);
    u += 0x7fffu + ((u >> 16) & 1u);
    return (unsigned short)(u >> 16);
}
__device__ __forceinline__ float bf2f(unsigned short h) {
    return __uint_as_float(((unsigned int)h) << 16);
}

// ---------------- async global->LDS, 16B per lane ----------------
__device__ __forceinline__ void gld16(const unsigned short* g, unsigned short* l) {
    __builtin_amdgcn_global_load_lds(
        (const __attribute__((address_space(1))) void*)g,
        (__attribute__((address_space(3))) void*)l,
        16, 0, 0);
}

// ---------------------------------------------------------------------------
// Shared 128x128 split-bf16 NT GEMM core: C(128x128 fp32 acc) +=
//   (Ah+Al)[m,k] * (Bh+Bl)[n,k]  (both operands row-major, K-contiguous)
// BK=32, mfma_f32_16x16x32_bf16, 256 thr = 4 waves, each wave 64x64 (4x4 tiles).
// LDS chunk layout [row][k] un-padded (required by global_load_lds).
// ---------------------------------------------------------------------------
__device__ __forceinline__ void gemm_core(
    const unsigned short* __restrict__ Agh, const unsigned short* __restrict__ Agl,
    const unsigned short* __restrict__ Bgh, const unsigned short* __restrict__ Bgl,
    int lda, int ldb, int K, long m0, long n0,
    unsigned short* As_h, unsigned short* As_l,
    unsigned short* Bs_h, unsigned short* Bs_l,
    f32x4 (&acc)[4][4])
{
    const int t = threadIdx.x;
    const int wave = t >> 6, lane = t & 63;
    const int wm = (wave & 1) * 64, wn = (wave >> 1) * 64;
    const int quad = lane >> 4, l16 = lane & 15;
    const int lr = lane >> 2;            // staging row within 16
    const int lc = (lane & 3) * 8;       // staging k-offset (elements)
    const int ar0 = wave * 32;           // chunk rows staged by this wave

    for (int k0 = 0; k0 < K; k0 += 32) {
        const size_t ga0 = (size_t)(m0 + ar0 + lr) * lda + k0 + lc;
        const size_t ga1 = ga0 + (size_t)16 * lda;
        const size_t gb0 = (size_t)(n0 + ar0 + lr) * ldb + k0 + lc;
        const size_t gb1 = gb0 + (size_t)16 * ldb;
        gld16(Agh + ga0, As_h + ar0 * 32);
        gld16(Agh + ga1, As_h + (ar0 + 16) * 32);
        gld16(Agl + ga0, As_l + ar0 * 32);
        gld16(Agl + ga1, As_l + (ar0 + 16) * 32);
        gld16(Bgh + gb0, Bs_h + ar0 * 32);
        gld16(Bgh + gb1, Bs_h + (ar0 + 16) * 32);
        gld16(Bgl + gb0, Bs_l + ar0 * 32);
        gld16(Bgl + gb1, Bs_l + (ar0 + 16) * 32);
        __syncthreads();

        short8 ah[4], al[4], bh[4], bl[4];
        #pragma unroll
        for (int i = 0; i < 4; ++i) {
            ah[i] = *(const short8*)&As_h[(wm + i * 16 + l16) * 32 + quad * 8];
            al[i] = *(const short8*)&As_l[(wm + i * 16 + l16) * 32 + quad * 8];
            bh[i] = *(const short8*)&Bs_h[(wn + i * 16 + l16) * 32 + quad * 8];
            bl[i] = *(const short8*)&Bs_l[(wn + i * 16 + l16) * 32 + quad * 8];
        }
        #pragma unroll
        for (int i = 0; i < 4; ++i)
            #pragma unroll
            for (int j = 0; j < 4; ++j) {
                acc[i][j] = __builtin_amdgcn_mfma_f32_16x16x32_bf16(ah[i], bh[j], acc[i][j], 0, 0, 0);
                acc[i][j] = __builtin_amdgcn_mfma_f32_16x16x32_bf16(ah[i], bl[j], acc[i][j], 0, 0, 0);
                acc[i][j] = __builtin_amdgcn_mfma_f32_16x16x32_bf16(al[i], bh[j], acc[i][j], 0, 0, 0);
            }
        __syncthreads();
    }
}

// ---------------------------------------------------------------------------
// Stage 1: k/q/v = X @ W^T + b.  z=0 -> K(h/l bf16), z=1 -> Q(fp32), z=2 -> V.
// ---------------------------------------------------------------------------
__global__ __launch_bounds__(256, 2) void qkv_mfma(
    const unsigned short* __restrict__ Xh, const unsigned short* __restrict__ Xl,
    const unsigned short* __restrict__ Wkh, const unsigned short* __restrict__ Wkl,
    const unsigned short* __restrict__ Wqh, const unsigned short* __restrict__ Wql,
    const unsigned short* __restrict__ Wvh, const unsigned short* __restrict__ Wvl,
    const float* __restrict__ bk, const float* __restrict__ bq, const float* __restrict__ bv,
    unsigned short* __restrict__ Kh, unsigned short* __restrict__ Kl,
    float* __restrict__ Qf,
    unsigned short* __restrict__ Vh, unsigned short* __restrict__ Vl)
{
    __shared__ unsigned short As_h[128 * 32], As_l[128 * 32], Bs_h[128 * 32], Bs_l[128 * 32];
    const int z = blockIdx.z;
    const unsigned short *Wh, *Wl; const float* bias;
    if (z == 0)      { Wh = Wkh; Wl = Wkl; bias = bk; }
    else if (z == 1) { Wh = Wqh; Wl = Wql; bias = bq; }
    else             { Wh = Wvh; Wl = Wvl; bias = bv; }

    const long m0 = (long)blockIdx.x * 128, n0 = (long)blockIdx.y * 128;
    f32x4 acc[4][4];
    #pragma unroll
    for (int i = 0; i < 4; ++i)
        #pragma unroll
        for (int j = 0; j < 4; ++j) acc[i][j] = (f32x4){0.f, 0.f, 0.f, 0.f};

    gemm_core(Xh, Xl, Wh, Wl, DD, DD, DD, m0, n0, As_h, As_l, Bs_h, Bs_l, acc);

    const int t = threadIdx.x, wave = t >> 6, lane = t & 63;
    const int wm = (wave & 1) * 64, wn = (wave >> 1) * 64;
    const int quad = lane >> 4, l16 = lane & 15;
    #pragma unroll
    for (int i = 0; i < 4; ++i)
        #pragma unroll
        for (int j = 0; j < 4; ++j) {
            const long col = n0 + wn + j * 16 + l16;
            const float bcol = bias[col];
            #pragma unroll
            for (int r = 0; r < 4; ++r) {
                const long row = m0 + wm + i * 16 + quad * 4 + r;
                const size_t idx = (size_t)row * DD + col;
                const float v = acc[i][j][r] + bcol;
                if (z == 1) {
                    Qf[idx] = v;
                } else {
                    const unsigned short h = f2bf(v);
                    const unsigned short lo = f2bf(v - bf2f(h));
                    if (z == 0) { Kh[idx] = h; Kl[idx] = lo; }
                    else        { Vh[idx] = h; Vl[idx] = lo; }
                }
            }
        }
}

// ---------------------------------------------------------------------------
// Stage 2: scoresT[e,d] = (1/32) * sum_s Vt[e,s] * Kt[d,s]  -> split bf16 h/l
// ---------------------------------------------------------------------------
__global__ __launch_bounds__(256, 2) void scores_mfma(
    const unsigned short* __restrict__ Vth, const unsigned short* __restrict__ Vtl,
    const unsigned short* __restrict__ Kth, const unsigned short* __restrict__ Ktl,
    unsigned short* __restrict__ Sh, unsigned short* __restrict__ Sl)
{
    __shared__ unsigned short As_h[128 * 32], As_l[128 * 32], Bs_h[128 * 32], Bs_l[128 * 32];
    const int b = blockIdx.z;
    const size_t tofs = (size_t)b * SS * DD;
    const long m0 = (long)blockIdx.x * 128, n0 = (long)blockIdx.y * 128;

    f32x4 acc[4][4];
    #pragma unroll
    for (int i = 0; i < 4; ++i)
        #pragma unroll
        for (int j = 0; j < 4; ++j) acc[i][j] = (f32x4){0.f, 0.f, 0.f, 0.f};

    gemm_core(Vth + tofs, Vtl + tofs, Kth + tofs, Ktl + tofs,
              SS, SS, SS, m0, n0, As_h, As_l, Bs_h, Bs_l, acc);

    const int t = threadIdx.x, wave = t >> 6, lane = t & 63;
    const int wm = (wave & 1) * 64, wn = (wave >> 1) * 64;
    const int quad = lane >> 4, l16 = lane & 15;
    const size_t bofs = (size_t)b * DD * DD;
    #pragma unroll
    for (int i = 0; i < 4; ++i)
        #pragma unroll
        for (int j = 0; j < 4; ++j) {
            const long col = n0 + wn + j * 16 + l16;
            #pragma unroll
            for (int r = 0; r < 4; ++r) {
                const long row = m0 + wm + i * 16 + quad * 4 + r;
                const float v = acc[i][j][r] * 0.03125f;
                const unsigned short h = f2bf(v);
                const unsigned short lo = f2bf(v - bf2f(h));
                const size_t idx = bofs + (size_t)row * DD + col;
                Sh[idx] = h; Sl[idx] = lo;
            }
        }
}

// ---------------------------------------------------------------------------
// Stage 4: out[s,e] = (1/32) * sum_d P[s,d] * scoresT[e,d]
// ---------------------------------------------------------------------------
__global__ __launch_bounds__(256, 2) void out_mfma(
    const unsigned short* __restrict__ Ph, const unsigned short* __restrict__ Pl,
    const unsigned short* __restrict__ Sh, const unsigned short* __restrict__ Sl,
    float* __restrict__ O)
{
    __shared__ unsigned short As_h[128 * 32], As_l[128 * 32], Bs_h[128 * 32], Bs_l[128 * 32];
    const long m0 = (long)blockIdx.x * 128, n0 = (long)blockIdx.y * 128;
    const int b = (int)(m0 >> 12);                // batch within group
    const size_t bofs = (size_t)b * DD * DD;

    f32x4 acc[4][4];
    #pragma unroll
    for (int i = 0; i < 4; ++i)
        #pragma unroll
        for (int j = 0; j < 4; ++j) acc[i][j] = (f32x4){0.f, 0.f, 0.f, 0.f};

    gemm_core(Ph, Pl, Sh + bofs, Sl + bofs,
              DD, DD, DD, m0, n0, As_h, As_l, Bs_h, Bs_l, acc);

    const int t = threadIdx.x, wave = t >> 6, lane = t & 63;
    const int wm = (wave & 1) * 64, wn = (wave >> 1) * 64;
    const int quad = lane >> 4, l16 = lane & 15;
    #pragma unroll
    for (int i = 0; i < 4; ++i)
        #pragma unroll
        for (int j = 0; j < 4; ++j) {
            const long col = n0 + wn + j * 16 + l16;
            #pragma unroll
            for (int r = 0; r < 4; ++r) {
                const long row = m0 + wm + i * 16 + quad * 4 + r;
                O[(size_t)row * DD + col] = acc[i][j][r] * 0.03125f;
            }
        }
}

// ---------------------------------------------------------------------------
// fp32 -> bf16 hi/lo split (vectorized, float4 in / ushort4 out)
// ---------------------------------------------------------------------------
__global__ __launch_bounds__(256) void split_fp32(
    const float4* __restrict__ in, unsigned short* __restrict__ h,
    unsigned short* __restrict__ l, long n4)
{
    const long i = (long)blockIdx.x * 256 + threadIdx.x;
    if (i >= n4) return;
    const float4 v = in[i];
    ushort4 hh, ll;
    hh.x = f2bf(v.x); ll.x = f2bf(v.x - bf2f(hh.x));
    hh.y = f2bf(v.y); ll.y = f2bf(v.y - bf2f(hh.y));
    hh.z = f2bf(v.z); ll.z = f2bf(v.z - bf2f(hh.z));
    hh.w = f2bf(v.w); ll.w = f2bf(v.w - bf2f(hh.w));
    *(ushort4*)(h + i * 4) = hh;
    *(ushort4*)(l + i * 4) = ll;
}

// ---------------------------------------------------------------------------
// bf16 [S,D] -> [D,S] tile transpose; z = batch*4 + {Kh,Kl,Vh,Vl}
// ---------------------------------------------------------------------------
__global__ __launch_bounds__(256) void transpose4(
    const unsigned short* __restrict__ Kh, const unsigned short* __restrict__ Kl,
    const unsigned short* __restrict__ Vh, const unsigned short* __restrict__ Vl,
    unsigned short* __restrict__ Kth, unsigned short* __restrict__ Ktl,
    unsigned short* __restrict__ Vth, unsigned short* __restrict__ Vtl)
{
    __shared__ unsigned short tile[64][65];
    const int z = blockIdx.z, b = z >> 2, sel = z & 3;
    const size_t bofs = (size_t)b * SS * DD;
    const unsigned short* in = (sel == 0 ? Kh : sel == 1 ? Kl : sel == 2 ? Vh : Vl) + bofs;
    unsigned short* outp     = (sel == 0 ? Kth : sel == 1 ? Ktl : sel == 2 ? Vth : Vtl) + bofs;

    const int s0 = blockIdx.x * 64, d0 = blockIdx.y * 64;
    const int t = threadIdx.x;
    const int c4 = t & 15, rbase = t >> 4;

    #pragma unroll
    for (int j = 0; j < 4; ++j) {
        const int r = j * 16 + rbase;                       // s_local
        const ushort4 v = *(const ushort4*)(in + (size_t)(s0 + r) * DD + d0 + c4 * 4);
        tile[r][c4 * 4 + 0] = v.x; tile[r][c4 * 4 + 1] = v.y;
        tile[r][c4 * 4 + 2] = v.z; tile[r][c4 * 4 + 3] = v.w;
    }
    __syncthreads();
    #pragma unroll
    for (int j = 0; j < 4; ++j) {
        const int rr = j * 16 + rbase;                      // d_local
        ushort4 v;
        v.x = tile[c4 * 4 + 0][rr]; v.y = tile[c4 * 4 + 1][rr];
        v.z = tile[c4 * 4 + 2][rr]; v.w = tile[c4 * 4 + 3][rr];
        *(ushort4*)(outp + (size_t)(d0 + rr) * SS + s0 + c4 * 4) = v;
    }
}

// ---------------------------------------------------------------------------
// Softmax over sequence axis; writes split bf16 P directly.
// ---------------------------------------------------------------------------
__global__ __launch_bounds__(256) void softmax_split(
    const float* __restrict__ Qf, unsigned short* __restrict__ Ph,
    unsigned short* __restrict__ Pl)
{
    const int d = blockIdx.x * 256 + threadIdx.x;
    const int b = blockIdx.y;
    const float* base = Qf + (size_t)b * SS * DD + d;

    float m = -INFINITY, l = 0.f;
    for (int s = 0; s < SS; ++s) {
        const float x = base[(size_t)s * DD];
        const float nm = fmaxf(m, x);
        l = l * __expf(m - nm) + __expf(x - nm);
        m = nm;
    }
    const float invl = 1.f / l;
    unsigned short* ph = Ph + (size_t)b * SS * DD + d;
    unsigned short* pl = Pl + (size_t)b * SS * DD + d;
    for (int s = 0; s < SS; ++s) {
        const float p = __expf(base[(size_t)s * DD] - m) * invl;
        const unsigned short h = f2bf(p);
        ph[(size_t)s * DD] = h;
        pl[(size_t)s * DD] = f2bf(p - bf2f(h));
    }
}

// ---------------------------------------------------------------------------
extern "C" void kernel_launch(void* const* d_in, const int* in_sizes, int n_in,
                              void* d_out, int out_size, void* d_ws, size_t ws_size,
                              hipStream_t stream)
{
    (void)in_sizes; (void)n_in; (void)out_size;
    const float* X  = (const float*)d_in[0];
    const float* Wk = (const float*)d_in[1];
    const float* bk = (const float*)d_in[2];
    const float* Wq = (const float*)d_in[3];
    const float* bq = (const float*)d_in[4];
    const float* Wv = (const float*)d_in[5];
    const float* bv = (const float*)d_in[6];
    float* out = (float*)d_out;

    const size_t SD = (size_t)SS * DD;           // 4M elems per batch-tensor
    const size_t WN = (size_t)DD * DD;           // 1M elems per weight

    // per-batch ws bytes: Xh/Xl(4*SD) + Kh/Kl/Vh/Vl(8*SD) + Qf(4*SD)
    //                   + Kt*(8*SD) + Sh/Sl(4*WN); Ph/Pl alias Xh/Xl.
    const size_t perBatch = 24 * SD + 4 * WN;
    const size_t wBytes = 6 * WN * 2;
    size_t usable = (ws_size > wBytes + (size_t)(1 << 16))
                        ? ws_size - wBytes - (size_t)(1 << 16) : 0;
    int G = (int)(usable / perBatch);
    if (G < 1) G = 1;
    if (G > BB) G = BB;

    char* p = (char*)d_ws;
    auto alloc = [&](size_t bytes) {
        char* q = p;
        p += (bytes + 255) & ~(size_t)255;
        return q;
    };
    unsigned short* Wkh = (unsigned short*)alloc(WN * 2);
    unsigned short* Wkl = (unsigned short*)alloc(WN * 2);
    unsigned short* Wqh = (unsigned short*)alloc(WN * 2);
    unsigned short* Wql = (unsigned short*)alloc(WN * 2);
    unsigned short* Wvh = (unsigned short*)alloc(WN * 2);
    unsigned short* Wvl = (unsigned short*)alloc(WN * 2);
    unsigned short* Xh  = (unsigned short*)alloc((size_t)G * SD * 2);
    unsigned short* Xl  = (unsigned short*)alloc((size_t)G * SD * 2);
    unsigned short* Kh  = (unsigned short*)alloc((size_t)G * SD * 2);
    unsigned short* Kl  = (unsigned short*)alloc((size_t)G * SD * 2);
    unsigned short* Vh  = (unsigned short*)alloc((size_t)G * SD * 2);
    unsigned short* Vl  = (unsigned short*)alloc((size_t)G * SD * 2);
    float*          Qf  = (float*)         alloc((size_t)G * SD * 4);
    unsigned short* Kth = (unsigned short*)alloc((size_t)G * SD * 2);
    unsigned short* Ktl = (unsigned short*)alloc((size_t)G * SD * 2);
    unsigned short* Vth = (unsigned short*)alloc((size_t)G * SD * 2);
    unsigned short* Vtl = (unsigned short*)alloc((size_t)G * SD * 2);
    unsigned short* Sh  = (unsigned short*)alloc((size_t)G * WN * 2);
    unsigned short* Sl  = (unsigned short*)alloc((size_t)G * WN * 2);
    unsigned short* Ph  = Xh;   // X dead after stage 1
    unsigned short* Pl  = Xl;

    // weights: split once per call
    split_fp32<<<dim3((unsigned)(WN / 4 / 256)), 256, 0, stream>>>((const float4*)Wk, Wkh, Wkl, (long)(WN / 4));
    split_fp32<<<dim3((unsigned)(WN / 4 / 256)), 256, 0, stream>>>((const float4*)Wq, Wqh, Wql, (long)(WN / 4));
    split_fp32<<<dim3((unsigned)(WN / 4 / 256)), 256, 0, stream>>>((const float4*)Wv, Wvh, Wvl, (long)(WN / 4));

    for (int b0 = 0; b0 < BB; b0 += G) {
        const int Gc = (b0 + G <= BB) ? G : (BB - b0);
        const float* Xg = X + (size_t)b0 * SD;

        const long n4 = (long)((size_t)Gc * SD / 4);
        split_fp32<<<dim3((unsigned)((n4 + 255) / 256)), 256, 0, stream>>>(
            (const float4*)Xg, Xh, Xl, n4);

        qkv_mfma<<<dim3(Gc * SS / 128, DD / 128, 3), 256, 0, stream>>>(
            Xh, Xl, Wkh, Wkl, Wqh, Wql, Wvh, Wvl, bk, bq, bv,
            Kh, Kl, Qf, Vh, Vl);

        transpose4<<<dim3(SS / 64, DD / 64, Gc * 4), 256, 0, stream>>>(
            Kh, Kl, Vh, Vl, Kth, Ktl, Vth, Vtl);

        softmax_split<<<dim3(DD / 256, Gc), 256, 0, stream>>>(Qf, Ph, Pl);

        scores_mfma<<<dim3(DD / 128, DD / 128, Gc), 256, 0, stream>>>(
            Vth, Vtl, Kth, Ktl, Sh, Sl);

        out_mfma<<<dim3(Gc * SS / 128, DD / 128), 256, 0, stream>>>(
            Ph, Pl, Sh, Sl, out + (size_t)b0 * SD);
    }
}

// Round 3
// 881.017 us; speedup vs baseline: 7.6904x; 4.1052x over previous
//
#include <hip/hip_runtime.h>
#include <math.h>

#define BB 8
#define SS 4096
#define DD 1024

typedef __attribute__((ext_vector_type(8))) short short8;   // 8 bf16 (4 VGPRs)
typedef __attribute__((ext_vector_type(4))) float f32x4;    // MFMA C/D

// ---------------- bf16 helpers (manual RNE) ----------------
__device__ __forceinline__ unsigned short f2bf(float x) {
    unsigned int u = __float_as_uint(x);
    u += 0x7fffu + ((u >> 16) & 1u);
    return (unsigned short)(u >> 16);
}

// ---------------- async global->LDS, 16B per lane ----------------
__device__ __forceinline__ void gld16(const unsigned short* g, unsigned short* l) {
    __builtin_amdgcn_global_load_lds(
        (const __attribute__((address_space(1))) void*)g,
        (__attribute__((address_space(3))) void*)l,
        16, 0, 0);
}

// ---------------------------------------------------------------------------
// 128x128 bf16 NT GEMM core: C += A[m,k] * B[n,k], both row-major K-contig.
// BK=32, mfma_f32_16x16x32_bf16, 256 thr = 4 waves, each wave 64x64 (4x4).
// LDS [row][k] un-padded (required by global_load_lds).
// ---------------------------------------------------------------------------
__device__ __forceinline__ void gemm_core1(
    const unsigned short* __restrict__ Ag, const unsigned short* __restrict__ Bg,
    int lda, int ldb, int K, long m0, long n0,
    unsigned short* As, unsigned short* Bs, f32x4 (&acc)[4][4])
{
    const int t = threadIdx.x;
    const int wave = t >> 6, lane = t & 63;
    const int wm = (wave & 1) * 64, wn = (wave >> 1) * 64;
    const int quad = lane >> 4, l16 = lane & 15;
    const int lr = lane >> 2;            // staging row within 16
    const int lc = (lane & 3) * 8;       // staging k-offset (elements)
    const int ar0 = wave * 32;           // chunk rows staged by this wave

    for (int k0 = 0; k0 < K; k0 += 32) {
        const size_t ga0 = (size_t)(m0 + ar0 + lr) * lda + k0 + lc;
        const size_t ga1 = ga0 + (size_t)16 * lda;
        const size_t gb0 = (size_t)(n0 + ar0 + lr) * ldb + k0 + lc;
        const size_t gb1 = gb0 + (size_t)16 * ldb;
        gld16(Ag + ga0, As + ar0 * 32);
        gld16(Ag + ga1, As + (ar0 + 16) * 32);
        gld16(Bg + gb0, Bs + ar0 * 32);
        gld16(Bg + gb1, Bs + (ar0 + 16) * 32);
        __syncthreads();

        short8 a[4], b[4];
        #pragma unroll
        for (int i = 0; i < 4; ++i) {
            a[i] = *(const short8*)&As[(wm + i * 16 + l16) * 32 + quad * 8];
            b[i] = *(const short8*)&Bs[(wn + i * 16 + l16) * 32 + quad * 8];
        }
        #pragma unroll
        for (int i = 0; i < 4; ++i)
            #pragma unroll
            for (int j = 0; j < 4; ++j)
                acc[i][j] = __builtin_amdgcn_mfma_f32_16x16x32_bf16(a[i], b[j], acc[i][j], 0, 0, 0);
        __syncthreads();
    }
}

// ---------------------------------------------------------------------------
// Stage 1: k/q/v = X @ W^T + b.  z=0 -> K(bf16), z=1 -> Q(fp32), z=2 -> V(bf16)
// ---------------------------------------------------------------------------
__global__ __launch_bounds__(256, 2) void qkv_bf16(
    const unsigned short* __restrict__ Xb,
    const unsigned short* __restrict__ Wkb, const unsigned short* __restrict__ Wqb,
    const unsigned short* __restrict__ Wvb,
    const float* __restrict__ bk, const float* __restrict__ bq, const float* __restrict__ bv,
    unsigned short* __restrict__ Kb, float* __restrict__ Qf, unsigned short* __restrict__ Vb)
{
    __shared__ unsigned short As[128 * 32], Bs[128 * 32];
    const int z = blockIdx.z;
    const unsigned short* W; const float* bias;
    if (z == 0)      { W = Wkb; bias = bk; }
    else if (z == 1) { W = Wqb; bias = bq; }
    else             { W = Wvb; bias = bv; }

    const long m0 = (long)blockIdx.x * 128, n0 = (long)blockIdx.y * 128;
    f32x4 acc[4][4];
    #pragma unroll
    for (int i = 0; i < 4; ++i)
        #pragma unroll
        for (int j = 0; j < 4; ++j) acc[i][j] = (f32x4){0.f, 0.f, 0.f, 0.f};

    gemm_core1(Xb, W, DD, DD, DD, m0, n0, As, Bs, acc);

    const int t = threadIdx.x, wave = t >> 6, lane = t & 63;
    const int wm = (wave & 1) * 64, wn = (wave >> 1) * 64;
    const int quad = lane >> 4, l16 = lane & 15;
    #pragma unroll
    for (int i = 0; i < 4; ++i)
        #pragma unroll
        for (int j = 0; j < 4; ++j) {
            const long col = n0 + wn + j * 16 + l16;
            const float bcol = bias[col];
            #pragma unroll
            for (int r = 0; r < 4; ++r) {
                const long row = m0 + wm + i * 16 + quad * 4 + r;
                const size_t idx = (size_t)row * DD + col;
                const float v = acc[i][j][r] + bcol;
                if (z == 1)      Qf[idx] = v;
                else if (z == 0) Kb[idx] = f2bf(v);
                else             Vb[idx] = f2bf(v);
            }
        }
}

// ---------------------------------------------------------------------------
// Stage 2: scoresT[e,d] = (1/32) * sum_s Vt[e,s] * Kt[d,s]  -> bf16
// ---------------------------------------------------------------------------
__global__ __launch_bounds__(256, 2) void scores_bf16(
    const unsigned short* __restrict__ Vt, const unsigned short* __restrict__ Kt,
    unsigned short* __restrict__ Sh)
{
    __shared__ unsigned short As[128 * 32], Bs[128 * 32];
    const int b = blockIdx.z;
    const size_t tofs = (size_t)b * SS * DD;
    const long m0 = (long)blockIdx.x * 128, n0 = (long)blockIdx.y * 128;

    f32x4 acc[4][4];
    #pragma unroll
    for (int i = 0; i < 4; ++i)
        #pragma unroll
        for (int j = 0; j < 4; ++j) acc[i][j] = (f32x4){0.f, 0.f, 0.f, 0.f};

    gemm_core1(Vt + tofs, Kt + tofs, SS, SS, SS, m0, n0, As, Bs, acc);

    const int t = threadIdx.x, wave = t >> 6, lane = t & 63;
    const int wm = (wave & 1) * 64, wn = (wave >> 1) * 64;
    const int quad = lane >> 4, l16 = lane & 15;
    const size_t bofs = (size_t)b * DD * DD;
    #pragma unroll
    for (int i = 0; i < 4; ++i)
        #pragma unroll
        for (int j = 0; j < 4; ++j) {
            const long col = n0 + wn + j * 16 + l16;
            #pragma unroll
            for (int r = 0; r < 4; ++r) {
                const long row = m0 + wm + i * 16 + quad * 4 + r;
                Sh[bofs + (size_t)row * DD + col] = f2bf(acc[i][j][r] * 0.03125f);
            }
        }
}

// ---------------------------------------------------------------------------
// Stage 4: out[s,e] = (1/32) * sum_d P[s,d] * scoresT[e,d]
// ---------------------------------------------------------------------------
__global__ __launch_bounds__(256, 2) void out_bf16(
    const unsigned short* __restrict__ Ph, const unsigned short* __restrict__ Sh,
    float* __restrict__ O)
{
    __shared__ unsigned short As[128 * 32], Bs[128 * 32];
    const long m0 = (long)blockIdx.x * 128, n0 = (long)blockIdx.y * 128;
    const int b = (int)(m0 >> 12);                // batch within group
    const size_t bofs = (size_t)b * DD * DD;

    f32x4 acc[4][4];
    #pragma unroll
    for (int i = 0; i < 4; ++i)
        #pragma unroll
        for (int j = 0; j < 4; ++j) acc[i][j] = (f32x4){0.f, 0.f, 0.f, 0.f};

    gemm_core1(Ph, Sh + bofs, DD, DD, DD, m0, n0, As, Bs, acc);

    const int t = threadIdx.x, wave = t >> 6, lane = t & 63;
    const int wm = (wave & 1) * 64, wn = (wave >> 1) * 64;
    const int quad = lane >> 4, l16 = lane & 15;
    #pragma unroll
    for (int i = 0; i < 4; ++i)
        #pragma unroll
        for (int j = 0; j < 4; ++j) {
            const long col = n0 + wn + j * 16 + l16;
            #pragma unroll
            for (int r = 0; r < 4; ++r) {
                const long row = m0 + wm + i * 16 + quad * 4 + r;
                O[(size_t)row * DD + col] = acc[i][j][r] * 0.03125f;
            }
        }
}

// ---------------------------------------------------------------------------
// fp32 -> bf16 cast (float4 in / ushort4 out)
// ---------------------------------------------------------------------------
__global__ __launch_bounds__(256) void cast_bf16(
    const float4* __restrict__ in, unsigned short* __restrict__ h, long n4)
{
    const long i = (long)blockIdx.x * 256 + threadIdx.x;
    if (i >= n4) return;
    const float4 v = in[i];
    ushort4 hh;
    hh.x = f2bf(v.x); hh.y = f2bf(v.y); hh.z = f2bf(v.z); hh.w = f2bf(v.w);
    *(ushort4*)(h + i * 4) = hh;
}

// ---------------------------------------------------------------------------
// bf16 [S,D] -> [D,S] tile transpose; z = batch*2 + {K,V}
// ---------------------------------------------------------------------------
__global__ __launch_bounds__(256) void transpose2(
    const unsigned short* __restrict__ Kb, const unsigned short* __restrict__ Vb,
    unsigned short* __restrict__ Kt, unsigned short* __restrict__ Vt)
{
    __shared__ unsigned short tile[64][65];
    const int z = blockIdx.z, b = z >> 1, sel = z & 1;
    const size_t bofs = (size_t)b * SS * DD;
    const unsigned short* in = (sel == 0 ? Kb : Vb) + bofs;
    unsigned short* outp     = (sel == 0 ? Kt : Vt) + bofs;

    const int s0 = blockIdx.x * 64, d0 = blockIdx.y * 64;
    const int t = threadIdx.x;
    const int c4 = t & 15, rbase = t >> 4;

    #pragma unroll
    for (int j = 0; j < 4; ++j) {
        const int r = j * 16 + rbase;                       // s_local
        const ushort4 v = *(const ushort4*)(in + (size_t)(s0 + r) * DD + d0 + c4 * 4);
        tile[r][c4 * 4 + 0] = v.x; tile[r][c4 * 4 + 1] = v.y;
        tile[r][c4 * 4 + 2] = v.z; tile[r][c4 * 4 + 3] = v.w;
    }
    __syncthreads();
    #pragma unroll
    for (int j = 0; j < 4; ++j) {
        const int rr = j * 16 + rbase;                      // d_local
        ushort4 v;
        v.x = tile[c4 * 4 + 0][rr]; v.y = tile[c4 * 4 + 1][rr];
        v.z = tile[c4 * 4 + 2][rr]; v.w = tile[c4 * 4 + 3][rr];
        *(ushort4*)(outp + (size_t)(d0 + rr) * SS + s0 + c4 * 4) = v;
    }
}

// ---------------------------------------------------------------------------
// Softmax over seq axis, parallelized: partial (per 512-row chunk) ->
// combine -> write (exp * inv_sum as bf16).
// ---------------------------------------------------------------------------
__global__ __launch_bounds__(256) void smax_partial(
    const float* __restrict__ Qf, float* __restrict__ Pm, float* __restrict__ Pl)
{
    __shared__ float sm[4][64], sl[4][64];
    const int t = threadIdx.x, tx = t & 63, ty = t >> 6;
    const int g = blockIdx.z;
    const int d = blockIdx.x * 64 + tx;
    const int s0 = blockIdx.y * 512 + ty * 128;
    const float* base = Qf + (size_t)g * SS * DD + (size_t)s0 * DD + d;

    float m = -INFINITY, l = 0.f;
    for (int r = 0; r < 128; ++r) {
        const float x = base[(size_t)r * DD];
        const float nm = fmaxf(m, x);
        l = l * __expf(m - nm) + __expf(x - nm);
        m = nm;
    }
    sm[ty][tx] = m; sl[ty][tx] = l;
    __syncthreads();
    if (t < 64) {
        float M = sm[0][t], L = sl[0][t];
        #pragma unroll
        for (int c = 1; c < 4; ++c) {
            const float mc = sm[c][t], lc = sl[c][t];
            const float nm = fmaxf(M, mc);
            L = L * __expf(M - nm) + lc * __expf(mc - nm);
            M = nm;
        }
        const size_t o = ((size_t)g * 8 + blockIdx.y) * DD + blockIdx.x * 64 + t;
        Pm[o] = M; Pl[o] = L;
    }
}

__global__ __launch_bounds__(256) void smax_combine(
    const float* __restrict__ Pm, const float* __restrict__ Pl,
    float* __restrict__ Fm, float* __restrict__ Fl)
{
    const int g = blockIdx.y;
    const int d = blockIdx.x * 256 + threadIdx.x;
    float M = -INFINITY, L = 0.f;
    #pragma unroll
    for (int c = 0; c < 8; ++c) {
        const size_t o = ((size_t)g * 8 + c) * DD + d;
        const float mc = Pm[o], lc = Pl[o];
        const float nm = fmaxf(M, mc);
        L = L * __expf(M - nm) + lc * __expf(mc - nm);
        M = nm;
    }
    Fm[(size_t)g * DD + d] = M;
    Fl[(size_t)g * DD + d] = 1.f / L;
}

__global__ __launch_bounds__(256) void smax_write(
    const float* __restrict__ Qf, const float* __restrict__ Fm,
    const float* __restrict__ Fl, unsigned short* __restrict__ Ph)
{
    const int t = threadIdx.x, tx = t & 63, ty = t >> 6;
    const int g = blockIdx.z;
    const int d = blockIdx.x * 64 + tx;
    const int s0 = blockIdx.y * 512 + ty * 128;
    const float M  = Fm[(size_t)g * DD + d];
    const float IL = Fl[(size_t)g * DD + d];
    const float* base = Qf + (size_t)g * SS * DD + (size_t)s0 * DD + d;
    unsigned short* pb = Ph + (size_t)g * SS * DD + (size_t)s0 * DD + d;
    for (int r = 0; r < 128; ++r) {
        const float p = __expf(base[(size_t)r * DD] - M) * IL;
        pb[(size_t)r * DD] = f2bf(p);
    }
}

// ---------------------------------------------------------------------------
extern "C" void kernel_launch(void* const* d_in, const int* in_sizes, int n_in,
                              void* d_out, int out_size, void* d_ws, size_t ws_size,
                              hipStream_t stream)
{
    (void)in_sizes; (void)n_in; (void)out_size;
    const float* X  = (const float*)d_in[0];
    const float* Wk = (const float*)d_in[1];
    const float* bk = (const float*)d_in[2];
    const float* Wq = (const float*)d_in[3];
    const float* bq = (const float*)d_in[4];
    const float* Wv = (const float*)d_in[5];
    const float* bv = (const float*)d_in[6];
    float* out = (float*)d_out;

    const size_t SD = (size_t)SS * DD;           // 4M elems
    const size_t WN = (size_t)DD * DD;           // 1M elems

    // per-batch ws bytes: Xb(2)+Kb(2)+Vb(2)+Qf(4)+Kt(2)+Vt(2) [*SD] + Sh(2*WN)
    // + softmax scratch (~70KB); Ph aliases Xb.
    const size_t perBatch = 14 * SD + 2 * WN + (size_t)(1 << 17);
    const size_t fixed = 3 * WN * 2 + (size_t)(1 << 20);
    size_t usable = (ws_size > fixed) ? ws_size - fixed : 0;
    int G = (int)(usable / perBatch);
    if (G < 1) G = 1;
    if (G > BB) G = BB;

    char* p = (char*)d_ws;
    auto alloc = [&](size_t bytes) {
        char* q = p;
        p += (bytes + 255) & ~(size_t)255;
        return q;
    };
    unsigned short* Wkb = (unsigned short*)alloc(WN * 2);
    unsigned short* Wqb = (unsigned short*)alloc(WN * 2);
    unsigned short* Wvb = (unsigned short*)alloc(WN * 2);
    unsigned short* Xb  = (unsigned short*)alloc((size_t)G * SD * 2);
    unsigned short* Kb  = (unsigned short*)alloc((size_t)G * SD * 2);
    unsigned short* Vb  = (unsigned short*)alloc((size_t)G * SD * 2);
    float*          Qf  = (float*)         alloc((size_t)G * SD * 4);
    unsigned short* Kt  = (unsigned short*)alloc((size_t)G * SD * 2);
    unsigned short* Vt  = (unsigned short*)alloc((size_t)G * SD * 2);
    unsigned short* Sh  = (unsigned short*)alloc((size_t)G * WN * 2);
    float*          Pm  = (float*)alloc((size_t)G * 8 * DD * 4);
    float*          Pl  = (float*)alloc((size_t)G * 8 * DD * 4);
    float*          Fm  = (float*)alloc((size_t)G * DD * 4);
    float*          Fl  = (float*)alloc((size_t)G * DD * 4);
    unsigned short* Ph  = Xb;   // X dead after stage 1

    // weights: cast once per call
    cast_bf16<<<dim3((unsigned)(WN / 4 / 256)), 256, 0, stream>>>((const float4*)Wk, Wkb, (long)(WN / 4));
    cast_bf16<<<dim3((unsigned)(WN / 4 / 256)), 256, 0, stream>>>((const float4*)Wq, Wqb, (long)(WN / 4));
    cast_bf16<<<dim3((unsigned)(WN / 4 / 256)), 256, 0, stream>>>((const float4*)Wv, Wvb, (long)(WN / 4));

    for (int b0 = 0; b0 < BB; b0 += G) {
        const int Gc = (b0 + G <= BB) ? G : (BB - b0);
        const float* Xg = X + (size_t)b0 * SD;

        const long n4 = (long)((size_t)Gc * SD / 4);
        cast_bf16<<<dim3((unsigned)((n4 + 255) / 256)), 256, 0, stream>>>(
            (const float4*)Xg, Xb, n4);

        qkv_bf16<<<dim3(Gc * SS / 128, DD / 128, 3), 256, 0, stream>>>(
            Xb, Wkb, Wqb, Wvb, bk, bq, bv, Kb, Qf, Vb);

        transpose2<<<dim3(SS / 64, DD / 64, Gc * 2), 256, 0, stream>>>(
            Kb, Vb, Kt, Vt);

        smax_partial<<<dim3(DD / 64, SS / 512, Gc), 256, 0, stream>>>(Qf, Pm, Pl);
        smax_combine<<<dim3(DD / 256, Gc), 256, 0, stream>>>(Pm, Pl, Fm, Fl);
        smax_write<<<dim3(DD / 64, SS / 512, Gc), 256, 0, stream>>>(Qf, Fm, Fl, Ph);

        scores_bf16<<<dim3(DD / 128, DD / 128, Gc), 256, 0, stream>>>(Vt, Kt, Sh);

        out_bf16<<<dim3(Gc * SS / 128, DD / 128), 256, 0, stream>>>(
            Ph, Sh, out + (size_t)b0 * SD);
    }
}